// Round 5
// baseline (153.401 us; speedup 1.0000x reference)
//
#include <hip/hip_runtime.h>
#include <math.h>

typedef unsigned short ushort_t;
typedef __attribute__((ext_vector_type(8))) short short8;
typedef __attribute__((ext_vector_type(4))) float f32x4;

#define B_N 4096
#define D_N 512
#define P_N 256
#define C_N 8

// workspace byte offsets
#define ACC_OFF   0                          // [0]=loss_sum, [1]=omega_sumsq
#define P2G_OFF   256                        // p2 grouped [256] f32
#define X2_OFF    1280                       // x2 [B][C] f32 (atomically accumulated)
#define XB_OFF    132352                     // x bf16 [B][D]
#define OMB_OFF   (XB_OFF + B_N*D_N*2)       // omega bf16 [C][D][D]
#define TPG_OFF   (OMB_OFF + C_N*D_N*D_N*2)  // tp grouped bf16 [C][32][D]
#define UG_OFF    (TPG_OFF + P_N*D_N*2)      // u grouped bf16 [C][32][D]
#define OMBT_OFF  (UG_OFF + P_N*D_N*2)       // omega^T bf16 [C][D][D]
#define DOTS_OFF  OMBT_OFF                   // dots [B][256] f32 — aliases ombT (dead by then; stream-ordered)

#define MFMA16(a, b, c) __builtin_amdgcn_mfma_f32_16x16x32_bf16(a, b, c, 0, 0, 0)

__device__ inline ushort_t f2bf(float f) {
    union { float f; unsigned u; } v; v.f = f;
    unsigned r = v.u + 0x7FFFu + ((v.u >> 16) & 1u);
    return (ushort_t)(r >> 16);
}

// ---------- cast x -> bf16 ----------
__global__ void k_cast_x(const float* __restrict__ x, ushort_t* __restrict__ xb) {
    int idx = blockIdx.x * 256 + threadIdx.x;
    const float4* x4 = (const float4*)x;
    float4 a = x4[idx * 2], b = x4[idx * 2 + 1];
    union { ushort_t s[8]; uint4 v; } o;
    o.s[0] = f2bf(a.x); o.s[1] = f2bf(a.y); o.s[2] = f2bf(a.z); o.s[3] = f2bf(a.w);
    o.s[4] = f2bf(b.x); o.s[5] = f2bf(b.y); o.s[6] = f2bf(b.z); o.s[7] = f2bf(b.w);
    ((uint4*)xb)[idx] = o.v;
}

// ---------- cast omega -> bf16 (row-major + transposed) + sumsq ----------
__global__ void k_cast_om(const float* __restrict__ omega, ushort_t* __restrict__ omb,
                          ushort_t* __restrict__ ombT, float* __restrict__ oss) {
    int c = blockIdx.z, r0 = blockIdx.y * 64, c0 = blockIdx.x * 64;
    __shared__ ushort_t T[64][72];
    __shared__ float red[4];
    int t = threadIdx.x;
    int r = t >> 2, seg = t & 3;
    const float* src = omega + ((size_t)c * D_N + r0 + r) * D_N + c0 + seg * 16;
    float4 v0 = ((const float4*)src)[0], v1 = ((const float4*)src)[1];
    float4 v2 = ((const float4*)src)[2], v3 = ((const float4*)src)[3];
    float s = v0.x*v0.x + v0.y*v0.y + v0.z*v0.z + v0.w*v0.w
            + v1.x*v1.x + v1.y*v1.y + v1.z*v1.z + v1.w*v1.w
            + v2.x*v2.x + v2.y*v2.y + v2.z*v2.z + v2.w*v2.w
            + v3.x*v3.x + v3.y*v3.y + v3.z*v3.z + v3.w*v3.w;
    union { ushort_t s[16]; uint4 v[2]; } o;
    float vv[16] = {v0.x,v0.y,v0.z,v0.w, v1.x,v1.y,v1.z,v1.w,
                    v2.x,v2.y,v2.z,v2.w, v3.x,v3.y,v3.z,v3.w};
    #pragma unroll
    for (int j = 0; j < 16; ++j) o.s[j] = f2bf(vv[j]);
    uint4* dst = (uint4*)(omb + ((size_t)c * D_N + r0 + r) * D_N + c0 + seg * 16);
    dst[0] = o.v[0]; dst[1] = o.v[1];
    #pragma unroll
    for (int j = 0; j < 16; ++j) T[seg * 16 + j][r] = o.s[j];
    __syncthreads();
    int jr = t >> 2, sg2 = t & 3;
    uint4 w0 = *(uint4*)&T[jr][sg2 * 16];
    uint4 w1 = *(uint4*)&T[jr][sg2 * 16 + 8];
    uint4* dstT = (uint4*)(ombT + ((size_t)c * D_N + c0 + jr) * D_N + r0 + sg2 * 16);
    dstT[0] = w0; dstT[1] = w1;
    #pragma unroll
    for (int off = 32; off > 0; off >>= 1) s += __shfl_down(s, off);
    if ((t & 63) == 0) red[t >> 6] = s;
    __syncthreads();
    if (t == 0) atomicAdd(oss, red[0] + red[1] + red[2] + red[3]);
}

// ---------- tp[c*32+m][i] = sum_k prot[c+8m][k] * om_c[i][k]; p2 fused ----------
__global__ __launch_bounds__(256) void k_tp(const float* __restrict__ prot,
                                            const ushort_t* __restrict__ omb,
                                            ushort_t* __restrict__ tpg,
                                            float* __restrict__ p2g) {
    int i0 = blockIdx.x * 64, c = blockIdx.y;
    __shared__ ushort_t As[32][72];
    __shared__ ushort_t Bs[64][72];
    int t = threadIdx.x, w = t >> 6, lane = t & 63;
    int g = lane >> 4, cl = lane & 15;
    f32x4 acc[2] = {{0,0,0,0},{0,0,0,0}};
    for (int k0 = 0; k0 < D_N; k0 += 64) {
        __syncthreads();
        {
            int m = t >> 3, seg = t & 7;
            const float* ap = prot + ((size_t)(c + 8 * m)) * D_N + k0 + seg * 8;
            float4 u0 = ((const float4*)ap)[0], u1 = ((const float4*)ap)[1];
            union { ushort_t s[8]; uint4 v; } o;
            o.s[0]=f2bf(u0.x); o.s[1]=f2bf(u0.y); o.s[2]=f2bf(u0.z); o.s[3]=f2bf(u0.w);
            o.s[4]=f2bf(u1.x); o.s[5]=f2bf(u1.y); o.s[6]=f2bf(u1.z); o.s[7]=f2bf(u1.w);
            *(uint4*)&As[m][seg * 8] = o.v;
        }
        {
            int r = t >> 2, sg = t & 3;
            const uint4* bp = (const uint4*)(omb + ((size_t)c * D_N + i0 + r) * D_N + k0 + sg * 16);
            *(uint4*)&Bs[r][sg * 16] = bp[0];
            *(uint4*)&Bs[r][sg * 16 + 8] = bp[1];
        }
        __syncthreads();
        #pragma unroll
        for (int kk = 0; kk < 2; ++kk) {
            int koff = kk * 32 + g * 8;
            short8 bfr = *(const short8*)&Bs[w * 16 + cl][koff];
            #pragma unroll
            for (int mt = 0; mt < 2; ++mt) {
                short8 afr = *(const short8*)&As[mt * 16 + cl][koff];
                acc[mt] = MFMA16(afr, bfr, acc[mt]);
            }
        }
    }
    #pragma unroll
    for (int mt = 0; mt < 2; ++mt)
        #pragma unroll
        for (int reg = 0; reg < 4; ++reg) {
            float v = acc[mt][reg];
            int m = mt * 16 + g * 4 + reg;
            int i = i0 + w * 16 + cl;
            tpg[((size_t)c * 32 + m) * D_N + i] = f2bf(v);
            float s = v * v;
            s += __shfl_xor(s, 1); s += __shfl_xor(s, 2);
            s += __shfl_xor(s, 4); s += __shfl_xor(s, 8);
            if (cl == 0) atomicAdd(&p2g[c * 32 + m], s);
        }
}

// ---------- u[c*32+m][j] = sum_i tp[c*32+m][i] * om_c[i][j] (uses ombT) ----------
__global__ __launch_bounds__(256) void k_u(const ushort_t* __restrict__ tpg,
                                           const ushort_t* __restrict__ ombT,
                                           ushort_t* __restrict__ ug) {
    int j0 = blockIdx.x * 64, c = blockIdx.y;
    __shared__ ushort_t As[32][72];
    __shared__ ushort_t Bs[64][72];
    int t = threadIdx.x, w = t >> 6, lane = t & 63;
    int g = lane >> 4, cl = lane & 15;
    f32x4 acc[2] = {{0,0,0,0},{0,0,0,0}};
    for (int k0 = 0; k0 < D_N; k0 += 64) {
        __syncthreads();
        {
            int m = t >> 3, seg = t & 7;
            *(uint4*)&As[m][seg * 8] =
                *(const uint4*)(tpg + ((size_t)c * 32 + m) * D_N + k0 + seg * 8);
        }
        {
            int r = t >> 2, sg = t & 3;
            const uint4* bp = (const uint4*)(ombT + ((size_t)c * D_N + j0 + r) * D_N + k0 + sg * 16);
            *(uint4*)&Bs[r][sg * 16] = bp[0];
            *(uint4*)&Bs[r][sg * 16 + 8] = bp[1];
        }
        __syncthreads();
        #pragma unroll
        for (int kk = 0; kk < 2; ++kk) {
            int koff = kk * 32 + g * 8;
            short8 bfr = *(const short8*)&Bs[w * 16 + cl][koff];
            #pragma unroll
            for (int mt = 0; mt < 2; ++mt) {
                short8 afr = *(const short8*)&As[mt * 16 + cl][koff];
                acc[mt] = MFMA16(afr, bfr, acc[mt]);
            }
        }
    }
    #pragma unroll
    for (int mt = 0; mt < 2; ++mt)
        #pragma unroll
        for (int reg = 0; reg < 4; ++reg) {
            int m = mt * 16 + g * 4 + reg;
            int j = j0 + w * 16 + cl;
            ug[((size_t)c * 32 + m) * D_N + j] = f2bf(acc[mt][reg]);
        }
}

// ---------- x2 partial + fused dots ----------
// grid (4 i-chunks, 8 c, 32 b-chunks), 256 thr. 128x128 x2-tile; wave quadrant 64x64.
// Blocks with i-chunk 0 additionally compute dots[b][c*32..c*32+32] (full K) riding
// on the X staging that's already there.
__global__ __launch_bounds__(256, 3) void k_x2d(const ushort_t* __restrict__ xb,
                                                const ushort_t* __restrict__ omb,
                                                const ushort_t* __restrict__ ug,
                                                float* __restrict__ x2,
                                                float* __restrict__ dots) {
    int i0 = blockIdx.x * 128;
    int c  = blockIdx.y;
    int b0 = blockIdx.z * 128;
    bool do_dots = (blockIdx.x == 0);
    __shared__ ushort_t Xs[128][72];
    __shared__ ushort_t Os[128][72];
    __shared__ ushort_t Us[32][72];
    __shared__ float red[128][2];
    int t = threadIdx.x, w = t >> 6, lane = t & 63;
    int qr = w >> 1, qc = w & 1;
    int g = lane >> 4, cl = lane & 15;
    f32x4 acc[4][4];
    #pragma unroll
    for (int mt = 0; mt < 4; ++mt)
        #pragma unroll
        for (int nt = 0; nt < 4; ++nt) acc[mt][nt] = (f32x4){0,0,0,0};
    f32x4 accd[2][2];
    #pragma unroll
    for (int m2 = 0; m2 < 2; ++m2)
        #pragma unroll
        for (int n2 = 0; n2 < 2; ++n2) accd[m2][n2] = (f32x4){0,0,0,0};

    for (int k0 = 0; k0 < D_N; k0 += 64) {
        __syncthreads();
        {
            int r = t >> 1, h = t & 1;
            const uint4* xp = (const uint4*)(xb + (size_t)(b0 + r) * D_N + k0 + h * 32);
            uint4* xd = (uint4*)&Xs[r][h * 32];
            xd[0] = xp[0]; xd[1] = xp[1]; xd[2] = xp[2]; xd[3] = xp[3];
            const uint4* op = (const uint4*)(omb + ((size_t)c * D_N + i0 + r) * D_N + k0 + h * 32);
            uint4* od = (uint4*)&Os[r][h * 32];
            od[0] = op[0]; od[1] = op[1]; od[2] = op[2]; od[3] = op[3];
        }
        if (do_dots) {
            int r = t >> 3, seg = t & 7;   // 32 rows x 8 segs = 256 threads
            *(uint4*)&Us[r][seg * 8] =
                *(const uint4*)(ug + ((size_t)c * 32 + r) * D_N + k0 + seg * 8);
        }
        __syncthreads();
        #pragma unroll
        for (int kk = 0; kk < 2; ++kk) {
            int koff = kk * 32 + g * 8;
            short8 a[4], b[4];
            #pragma unroll
            for (int mt = 0; mt < 4; ++mt)
                a[mt] = *(const short8*)&Xs[qr * 64 + mt * 16 + cl][koff];
            #pragma unroll
            for (int nt = 0; nt < 4; ++nt)
                b[nt] = *(const short8*)&Os[qc * 64 + nt * 16 + cl][koff];
            #pragma unroll
            for (int mt = 0; mt < 4; ++mt)
                #pragma unroll
                for (int nt = 0; nt < 4; ++nt)
                    acc[mt][nt] = MFMA16(a[mt], b[nt], acc[mt][nt]);
            if (do_dots) {
                short8 ad[2], bd[2];
                #pragma unroll
                for (int m2 = 0; m2 < 2; ++m2)
                    ad[m2] = *(const short8*)&Xs[w * 32 + m2 * 16 + cl][koff];
                #pragma unroll
                for (int n2 = 0; n2 < 2; ++n2)
                    bd[n2] = *(const short8*)&Us[n2 * 16 + cl][koff];
                #pragma unroll
                for (int m2 = 0; m2 < 2; ++m2)
                    #pragma unroll
                    for (int n2 = 0; n2 < 2; ++n2)
                        accd[m2][n2] = MFMA16(ad[m2], bd[n2], accd[m2][n2]);
            }
        }
    }
    // x2 epilogue: row-sum of squares, 2-stage reduce, atomic add
    #pragma unroll
    for (int mt = 0; mt < 4; ++mt)
        #pragma unroll
        for (int reg = 0; reg < 4; ++reg) {
            float s = 0.f;
            #pragma unroll
            for (int nt = 0; nt < 4; ++nt) s += acc[mt][nt][reg] * acc[mt][nt][reg];
            s += __shfl_xor(s, 1); s += __shfl_xor(s, 2);
            s += __shfl_xor(s, 4); s += __shfl_xor(s, 8);
            if (cl == 0) red[qr * 64 + mt * 16 + g * 4 + reg][qc] = s;
        }
    __syncthreads();
    if (t < 128) atomicAdd(&x2[(size_t)(b0 + t) * C_N + c], red[t][0] + red[t][1]);
    // dots epilogue: plain store (unique writer per element)
    if (do_dots) {
        #pragma unroll
        for (int m2 = 0; m2 < 2; ++m2)
            #pragma unroll
            for (int n2 = 0; n2 < 2; ++n2)
                #pragma unroll
                for (int reg = 0; reg < 4; ++reg) {
                    int b = b0 + w * 32 + m2 * 16 + g * 4 + reg;
                    int q = c * 32 + n2 * 16 + cl;
                    dots[(size_t)b * P_N + q] = accd[m2][n2][reg];
                }
    }
}

// ---------- per-row mins -> mu -> sigmoid -> sum ----------
__global__ void k_mu(const float* __restrict__ dots, const float* __restrict__ x2,
                     const float* __restrict__ p2g, const int* __restrict__ y,
                     float* __restrict__ acc) {
    int t = threadIdx.x, w = t >> 6, lane = t & 63;
    int b = blockIdx.x * 4 + w;
    __shared__ float red[4];
    int yb = y[b];
    float pos = INFINITY, neg = INFINITY;
    #pragma unroll
    for (int j = 0; j < 4; ++j) {
        int q = lane + j * 64;
        int lab = q >> 5;
        float dist = x2[(size_t)b * C_N + lab] + p2g[q] - 2.f * dots[(size_t)b * P_N + q];
        if (lab == yb) pos = fminf(pos, dist);
        else           neg = fminf(neg, dist);
    }
    #pragma unroll
    for (int off = 32; off > 0; off >>= 1) {
        pos = fminf(pos, __shfl_xor(pos, off));
        neg = fminf(neg, __shfl_xor(neg, off));
    }
    if (lane == 0) {
        float mu = (pos - neg) / (pos + neg);
        red[w] = 1.f / (1.f + expf(-mu));
    }
    __syncthreads();
    if (t == 0) atomicAdd(acc, red[0] + red[1] + red[2] + red[3]);
}

__global__ void k_final(const float* __restrict__ accs, float* __restrict__ out) {
    out[0] = accs[0] * (1.f / (float)B_N) + 0.01f * sqrtf(accs[1]);
}

extern "C" void kernel_launch(void* const* d_in, const int* in_sizes, int n_in,
                              void* d_out, int out_size, void* d_ws, size_t ws_size,
                              hipStream_t stream) {
    (void)in_sizes; (void)n_in; (void)out_size; (void)ws_size;
    const float* x     = (const float*)d_in[0];
    const int*   y     = (const int*)d_in[1];
    const float* prot  = (const float*)d_in[2];
    const float* omega = (const float*)d_in[3];

    char* ws = (char*)d_ws;
    float*    accs = (float*)(ws + ACC_OFF);
    float*    p2g  = (float*)(ws + P2G_OFF);
    float*    x2   = (float*)(ws + X2_OFF);
    ushort_t* xb   = (ushort_t*)(ws + XB_OFF);
    ushort_t* omb  = (ushort_t*)(ws + OMB_OFF);
    ushort_t* tpg  = (ushort_t*)(ws + TPG_OFF);
    ushort_t* ug   = (ushort_t*)(ws + UG_OFF);
    ushort_t* ombT = (ushort_t*)(ws + OMBT_OFF);
    float*    dots = (float*)(ws + DOTS_OFF);  // aliases ombT — safe: stream-ordered after k_u

    (void)hipMemsetAsync(ws, 0, XB_OFF, stream);  // accs, p2g, x2
    k_cast_x <<<B_N * D_N / 8 / 256, 256, 0, stream>>>(x, xb);
    k_cast_om<<<dim3(8, 8, C_N), 256, 0, stream>>>(omega, omb, ombT, accs + 1);
    k_tp     <<<dim3(8, C_N), 256, 0, stream>>>(prot, omb, tpg, p2g);
    k_u      <<<dim3(8, C_N), 256, 0, stream>>>(tpg, ombT, ug);
    k_x2d    <<<dim3(4, C_N, B_N / 128), 256, 0, stream>>>(xb, omb, ug, x2, dots);
    k_mu     <<<B_N / 4, 256, 0, stream>>>(dots, x2, p2g, y, accs);
    k_final  <<<1, 1, 0, stream>>>(accs, (float*)d_out);
}

// Round 6
// 141.417 us; speedup vs baseline: 1.0847x; 1.0847x over previous
//
#include <hip/hip_runtime.h>
#include <math.h>

typedef unsigned short ushort_t;
typedef __attribute__((ext_vector_type(8))) short short8;
typedef __attribute__((ext_vector_type(4))) float f32x4;

#define B_N 4096
#define D_N 512
#define P_N 256
#define C_N 8

// workspace byte offsets
#define ACC_OFF   0                          // [0]=loss_sum, [1]=omega_sumsq
#define P2G_OFF   256                        // p2 grouped [256] f32
#define X2_OFF    1280                       // x2 [B][C] f32 (atomically accumulated)
#define XB_OFF    132352                     // x bf16 [B][D]
#define OMB_OFF   (XB_OFF + B_N*D_N*2)       // omega bf16 [C][D][D]
#define TPG_OFF   (OMB_OFF + C_N*D_N*D_N*2)  // tp grouped bf16 [C][32][D]
#define UG_OFF    (TPG_OFF + P_N*D_N*2)      // u grouped bf16 [C][32][D]
#define OMBT_OFF  (UG_OFF + P_N*D_N*2)       // omega^T bf16 [C][D][D]
#define DOTS_OFF  OMBT_OFF                   // dots [B][256] f32 — aliases ombT (dead after k_u; stream-ordered)

#define MFMA16(a, b, c) __builtin_amdgcn_mfma_f32_16x16x32_bf16(a, b, c, 0, 0, 0)

__device__ inline ushort_t f2bf(float f) {
    union { float f; unsigned u; } v; v.f = f;
    unsigned r = v.u + 0x7FFFu + ((v.u >> 16) & 1u);
    return (ushort_t)(r >> 16);
}

// async global->LDS, 16 B per lane. LDS dst must be wave-uniform; HW writes base + lane*16.
__device__ __forceinline__ void gll16(const ushort_t* g, ushort_t* l) {
    __builtin_amdgcn_global_load_lds((const __attribute__((address_space(1))) void*)g,
                                     (__attribute__((address_space(3))) void*)l, 16, 0, 0);
}

// ---------- cast x -> bf16 ----------
__global__ void k_cast_x(const float* __restrict__ x, ushort_t* __restrict__ xb) {
    int idx = blockIdx.x * 256 + threadIdx.x;
    const float4* x4 = (const float4*)x;
    float4 a = x4[idx * 2], b = x4[idx * 2 + 1];
    union { ushort_t s[8]; uint4 v; } o;
    o.s[0] = f2bf(a.x); o.s[1] = f2bf(a.y); o.s[2] = f2bf(a.z); o.s[3] = f2bf(a.w);
    o.s[4] = f2bf(b.x); o.s[5] = f2bf(b.y); o.s[6] = f2bf(b.z); o.s[7] = f2bf(b.w);
    ((uint4*)xb)[idx] = o.v;
}

// ---------- cast omega -> bf16 (row-major + transposed) + sumsq ----------
__global__ void k_cast_om(const float* __restrict__ omega, ushort_t* __restrict__ omb,
                          ushort_t* __restrict__ ombT, float* __restrict__ oss) {
    int c = blockIdx.z, r0 = blockIdx.y * 64, c0 = blockIdx.x * 64;
    __shared__ ushort_t T[64][72];
    __shared__ float red[4];
    int t = threadIdx.x;
    int r = t >> 2, seg = t & 3;
    const float* src = omega + ((size_t)c * D_N + r0 + r) * D_N + c0 + seg * 16;
    float4 v0 = ((const float4*)src)[0], v1 = ((const float4*)src)[1];
    float4 v2 = ((const float4*)src)[2], v3 = ((const float4*)src)[3];
    float s = v0.x*v0.x + v0.y*v0.y + v0.z*v0.z + v0.w*v0.w
            + v1.x*v1.x + v1.y*v1.y + v1.z*v1.z + v1.w*v1.w
            + v2.x*v2.x + v2.y*v2.y + v2.z*v2.z + v2.w*v2.w
            + v3.x*v3.x + v3.y*v3.y + v3.z*v3.z + v3.w*v3.w;
    union { ushort_t s[16]; uint4 v[2]; } o;
    float vv[16] = {v0.x,v0.y,v0.z,v0.w, v1.x,v1.y,v1.z,v1.w,
                    v2.x,v2.y,v2.z,v2.w, v3.x,v3.y,v3.z,v3.w};
    #pragma unroll
    for (int j = 0; j < 16; ++j) o.s[j] = f2bf(vv[j]);
    uint4* dst = (uint4*)(omb + ((size_t)c * D_N + r0 + r) * D_N + c0 + seg * 16);
    dst[0] = o.v[0]; dst[1] = o.v[1];
    #pragma unroll
    for (int j = 0; j < 16; ++j) T[seg * 16 + j][r] = o.s[j];
    __syncthreads();
    int jr = t >> 2, sg2 = t & 3;
    uint4 w0 = *(uint4*)&T[jr][sg2 * 16];
    uint4 w1 = *(uint4*)&T[jr][sg2 * 16 + 8];
    uint4* dstT = (uint4*)(ombT + ((size_t)c * D_N + c0 + jr) * D_N + r0 + sg2 * 16);
    dstT[0] = w0; dstT[1] = w1;
    #pragma unroll
    for (int off = 32; off > 0; off >>= 1) s += __shfl_down(s, off);
    if ((t & 63) == 0) red[t >> 6] = s;
    __syncthreads();
    if (t == 0) atomicAdd(oss, red[0] + red[1] + red[2] + red[3]);
}

// ---------- tp[c*32+m][i] = sum_k prot[c+8m][k] * om_c[i][k]; p2 fused ----------
__global__ __launch_bounds__(256) void k_tp(const float* __restrict__ prot,
                                            const ushort_t* __restrict__ omb,
                                            ushort_t* __restrict__ tpg,
                                            float* __restrict__ p2g) {
    int i0 = blockIdx.x * 64, c = blockIdx.y;
    __shared__ ushort_t As[32][72];
    __shared__ ushort_t Bs[64][72];
    int t = threadIdx.x, w = t >> 6, lane = t & 63;
    int g = lane >> 4, cl = lane & 15;
    f32x4 acc[2] = {{0,0,0,0},{0,0,0,0}};
    for (int k0 = 0; k0 < D_N; k0 += 64) {
        __syncthreads();
        {
            int m = t >> 3, seg = t & 7;
            const float* ap = prot + ((size_t)(c + 8 * m)) * D_N + k0 + seg * 8;
            float4 u0 = ((const float4*)ap)[0], u1 = ((const float4*)ap)[1];
            union { ushort_t s[8]; uint4 v; } o;
            o.s[0]=f2bf(u0.x); o.s[1]=f2bf(u0.y); o.s[2]=f2bf(u0.z); o.s[3]=f2bf(u0.w);
            o.s[4]=f2bf(u1.x); o.s[5]=f2bf(u1.y); o.s[6]=f2bf(u1.z); o.s[7]=f2bf(u1.w);
            *(uint4*)&As[m][seg * 8] = o.v;
        }
        {
            int r = t >> 2, sg = t & 3;
            const uint4* bp = (const uint4*)(omb + ((size_t)c * D_N + i0 + r) * D_N + k0 + sg * 16);
            *(uint4*)&Bs[r][sg * 16] = bp[0];
            *(uint4*)&Bs[r][sg * 16 + 8] = bp[1];
        }
        __syncthreads();
        #pragma unroll
        for (int kk = 0; kk < 2; ++kk) {
            int koff = kk * 32 + g * 8;
            short8 bfr = *(const short8*)&Bs[w * 16 + cl][koff];
            #pragma unroll
            for (int mt = 0; mt < 2; ++mt) {
                short8 afr = *(const short8*)&As[mt * 16 + cl][koff];
                acc[mt] = MFMA16(afr, bfr, acc[mt]);
            }
        }
    }
    #pragma unroll
    for (int mt = 0; mt < 2; ++mt)
        #pragma unroll
        for (int reg = 0; reg < 4; ++reg) {
            float v = acc[mt][reg];
            int m = mt * 16 + g * 4 + reg;
            int i = i0 + w * 16 + cl;
            tpg[((size_t)c * 32 + m) * D_N + i] = f2bf(v);
            float s = v * v;
            s += __shfl_xor(s, 1); s += __shfl_xor(s, 2);
            s += __shfl_xor(s, 4); s += __shfl_xor(s, 8);
            if (cl == 0) atomicAdd(&p2g[c * 32 + m], s);
        }
}

// ---------- u[c*32+m][j] = sum_i tp[c*32+m][i] * om_c[i][j] (uses ombT) ----------
__global__ __launch_bounds__(256) void k_u(const ushort_t* __restrict__ tpg,
                                           const ushort_t* __restrict__ ombT,
                                           ushort_t* __restrict__ ug) {
    int j0 = blockIdx.x * 64, c = blockIdx.y;
    __shared__ ushort_t As[32][72];
    __shared__ ushort_t Bs[64][72];
    int t = threadIdx.x, w = t >> 6, lane = t & 63;
    int g = lane >> 4, cl = lane & 15;
    f32x4 acc[2] = {{0,0,0,0},{0,0,0,0}};
    for (int k0 = 0; k0 < D_N; k0 += 64) {
        __syncthreads();
        {
            int m = t >> 3, seg = t & 7;
            *(uint4*)&As[m][seg * 8] =
                *(const uint4*)(tpg + ((size_t)c * 32 + m) * D_N + k0 + seg * 8);
        }
        {
            int r = t >> 2, sg = t & 3;
            const uint4* bp = (const uint4*)(ombT + ((size_t)c * D_N + j0 + r) * D_N + k0 + sg * 16);
            *(uint4*)&Bs[r][sg * 16] = bp[0];
            *(uint4*)&Bs[r][sg * 16 + 8] = bp[1];
        }
        __syncthreads();
        #pragma unroll
        for (int kk = 0; kk < 2; ++kk) {
            int koff = kk * 32 + g * 8;
            short8 bfr = *(const short8*)&Bs[w * 16 + cl][koff];
            #pragma unroll
            for (int mt = 0; mt < 2; ++mt) {
                short8 afr = *(const short8*)&As[mt * 16 + cl][koff];
                acc[mt] = MFMA16(afr, bfr, acc[mt]);
            }
        }
    }
    #pragma unroll
    for (int mt = 0; mt < 2; ++mt)
        #pragma unroll
        for (int reg = 0; reg < 4; ++reg) {
            int m = mt * 16 + g * 4 + reg;
            int j = j0 + w * 16 + cl;
            ug[((size_t)c * 32 + m) * D_N + j] = f2bf(acc[mt][reg]);
        }
}

// ---------- x2 partial: block (i-chunk, c, b-chunk) adds ||om_c[i0:i0+128] x_b||^2 ----------
// grid (4, 8, 32), 256 thr, 4 blocks/CU (33 KB LDS). Async global_load_lds staging with
// source-permutation swizzle: LDS chunk-position p of row r holds global chunk (p+r)&7.
__global__ __launch_bounds__(256, 4) void k_x2(const ushort_t* __restrict__ xb,
                                               const ushort_t* __restrict__ omb,
                                               float* __restrict__ x2) {
    int i0 = blockIdx.x * 128;
    int c  = blockIdx.y;
    int b0 = blockIdx.z * 128;
    __shared__ ushort_t Xs[128][64];   // unpadded (global_load_lds requires contiguity)
    __shared__ ushort_t Os[128][64];
    __shared__ float red[128][2];
    int t = threadIdx.x, w = t >> 6, lane = t & 63;
    int qr = w >> 1, qc = w & 1;
    int g = lane >> 4, cl = lane & 15;
    int lrow = lane >> 3, lpos = lane & 7;   // staging: 8 rows x 8 chunk-positions per instr
    f32x4 acc[4][4];
    #pragma unroll
    for (int mt = 0; mt < 4; ++mt)
        #pragma unroll
        for (int nt = 0; nt < 4; ++nt) acc[mt][nt] = (f32x4){0,0,0,0};

    for (int k0 = 0; k0 < D_N; k0 += 64) {
        __syncthreads();   // previous slab's reads done before overwrite
        #pragma unroll
        for (int i = 0; i < 4; ++i) {
            int rb = w * 32 + i * 8;
            int r  = rb + lrow;
            int cg = (lpos + r) & 7;          // swizzle: this lane fetches global chunk cg
            gll16(xb + (size_t)(b0 + r) * D_N + k0 + cg * 8, &Xs[rb][0]);
            gll16(omb + ((size_t)c * D_N + i0 + r) * D_N + k0 + cg * 8, &Os[rb][0]);
        }
        __syncthreads();   // drains vmcnt(0) then barrier
        #pragma unroll
        for (int kk = 0; kk < 2; ++kk) {
            int p8 = ((kk * 4 + g - cl) & 7) * 8;   // LDS position of global chunk kk*4+g in row ≡ cl (mod 8)
            short8 a[4], b[4];
            #pragma unroll
            for (int mt = 0; mt < 4; ++mt)
                a[mt] = *(const short8*)&Xs[qr * 64 + mt * 16 + cl][p8];
            #pragma unroll
            for (int nt = 0; nt < 4; ++nt)
                b[nt] = *(const short8*)&Os[qc * 64 + nt * 16 + cl][p8];
            #pragma unroll
            for (int mt = 0; mt < 4; ++mt)
                #pragma unroll
                for (int nt = 0; nt < 4; ++nt)
                    acc[mt][nt] = MFMA16(a[mt], b[nt], acc[mt][nt]);
        }
    }
    #pragma unroll
    for (int mt = 0; mt < 4; ++mt)
        #pragma unroll
        for (int reg = 0; reg < 4; ++reg) {
            float s = 0.f;
            #pragma unroll
            for (int nt = 0; nt < 4; ++nt) s += acc[mt][nt][reg] * acc[mt][nt][reg];
            s += __shfl_xor(s, 1); s += __shfl_xor(s, 2);
            s += __shfl_xor(s, 4); s += __shfl_xor(s, 8);
            if (cl == 0) red[qr * 64 + mt * 16 + g * 4 + reg][qc] = s;
        }
    __syncthreads();
    if (t < 128) atomicAdd(&x2[(size_t)(b0 + t) * C_N + c], red[t][0] + red[t][1]);
}

// ---------- dots[b][q] = x_b . u_q — MFMA, grid (B/64, 256/64) ----------
__global__ __launch_bounds__(256) void k_dots(const ushort_t* __restrict__ xb,
                                              const ushort_t* __restrict__ ug,
                                              float* __restrict__ dots) {
    int b0 = blockIdx.x * 64, q0 = blockIdx.y * 64;
    __shared__ ushort_t Xs[64][72];
    __shared__ ushort_t Us[64][72];
    int t = threadIdx.x, w = t >> 6, lane = t & 63;
    int qr = w >> 1, qc = w & 1;
    int g = lane >> 4, cl = lane & 15;
    f32x4 acc[2][2];
    #pragma unroll
    for (int mt = 0; mt < 2; ++mt)
        #pragma unroll
        for (int nt = 0; nt < 2; ++nt) acc[mt][nt] = (f32x4){0,0,0,0};
    for (int k0 = 0; k0 < D_N; k0 += 64) {
        __syncthreads();
        {
            int r = t >> 2, sg = t & 3;
            const uint4* xp = (const uint4*)(xb + (size_t)(b0 + r) * D_N + k0 + sg * 16);
            *(uint4*)&Xs[r][sg * 16] = xp[0];
            *(uint4*)&Xs[r][sg * 16 + 8] = xp[1];
            const uint4* up = (const uint4*)(ug + (size_t)(q0 + r) * D_N + k0 + sg * 16);
            *(uint4*)&Us[r][sg * 16] = up[0];
            *(uint4*)&Us[r][sg * 16 + 8] = up[1];
        }
        __syncthreads();
        #pragma unroll
        for (int kk = 0; kk < 2; ++kk) {
            int koff = kk * 32 + g * 8;
            short8 a[2], b[2];
            #pragma unroll
            for (int mt = 0; mt < 2; ++mt)
                a[mt] = *(const short8*)&Xs[qr * 32 + mt * 16 + cl][koff];
            #pragma unroll
            for (int nt = 0; nt < 2; ++nt)
                b[nt] = *(const short8*)&Us[qc * 32 + nt * 16 + cl][koff];
            #pragma unroll
            for (int mt = 0; mt < 2; ++mt)
                #pragma unroll
                for (int nt = 0; nt < 2; ++nt)
                    acc[mt][nt] = MFMA16(a[mt], b[nt], acc[mt][nt]);
        }
    }
    #pragma unroll
    for (int mt = 0; mt < 2; ++mt)
        #pragma unroll
        for (int nt = 0; nt < 2; ++nt)
            #pragma unroll
            for (int reg = 0; reg < 4; ++reg) {
                int b = b0 + qr * 32 + mt * 16 + g * 4 + reg;
                int q = q0 + qc * 32 + nt * 16 + cl;
                dots[(size_t)b * P_N + q] = acc[mt][nt][reg];
            }
}

// ---------- per-row mins -> mu -> sigmoid -> sum ----------
__global__ void k_mu(const float* __restrict__ dots, const float* __restrict__ x2,
                     const float* __restrict__ p2g, const int* __restrict__ y,
                     float* __restrict__ acc) {
    int t = threadIdx.x, w = t >> 6, lane = t & 63;
    int b = blockIdx.x * 4 + w;
    __shared__ float red[4];
    int yb = y[b];
    float pos = INFINITY, neg = INFINITY;
    #pragma unroll
    for (int j = 0; j < 4; ++j) {
        int q = lane + j * 64;
        int lab = q >> 5;
        float dist = x2[(size_t)b * C_N + lab] + p2g[q] - 2.f * dots[(size_t)b * P_N + q];
        if (lab == yb) pos = fminf(pos, dist);
        else           neg = fminf(neg, dist);
    }
    #pragma unroll
    for (int off = 32; off > 0; off >>= 1) {
        pos = fminf(pos, __shfl_xor(pos, off));
        neg = fminf(neg, __shfl_xor(neg, off));
    }
    if (lane == 0) {
        float mu = (pos - neg) / (pos + neg);
        red[w] = 1.f / (1.f + expf(-mu));
    }
    __syncthreads();
    if (t == 0) atomicAdd(acc, red[0] + red[1] + red[2] + red[3]);
}

__global__ void k_final(const float* __restrict__ accs, float* __restrict__ out) {
    out[0] = accs[0] * (1.f / (float)B_N) + 0.01f * sqrtf(accs[1]);
}

extern "C" void kernel_launch(void* const* d_in, const int* in_sizes, int n_in,
                              void* d_out, int out_size, void* d_ws, size_t ws_size,
                              hipStream_t stream) {
    (void)in_sizes; (void)n_in; (void)out_size; (void)ws_size;
    const float* x     = (const float*)d_in[0];
    const int*   y     = (const int*)d_in[1];
    const float* prot  = (const float*)d_in[2];
    const float* omega = (const float*)d_in[3];

    char* ws = (char*)d_ws;
    float*    accs = (float*)(ws + ACC_OFF);
    float*    p2g  = (float*)(ws + P2G_OFF);
    float*    x2   = (float*)(ws + X2_OFF);
    ushort_t* xb   = (ushort_t*)(ws + XB_OFF);
    ushort_t* omb  = (ushort_t*)(ws + OMB_OFF);
    ushort_t* tpg  = (ushort_t*)(ws + TPG_OFF);
    ushort_t* ug   = (ushort_t*)(ws + UG_OFF);
    ushort_t* ombT = (ushort_t*)(ws + OMBT_OFF);
    float*    dots = (float*)(ws + DOTS_OFF);  // aliases ombT — safe: stream-ordered after k_u

    (void)hipMemsetAsync(ws, 0, XB_OFF, stream);  // accs, p2g, x2
    k_cast_x <<<B_N * D_N / 8 / 256, 256, 0, stream>>>(x, xb);
    k_cast_om<<<dim3(8, 8, C_N), 256, 0, stream>>>(omega, omb, ombT, accs + 1);
    k_tp     <<<dim3(8, C_N), 256, 0, stream>>>(prot, omb, tpg, p2g);
    k_u      <<<dim3(8, C_N), 256, 0, stream>>>(tpg, ombT, ug);
    k_x2     <<<dim3(4, C_N, B_N / 128), 256, 0, stream>>>(xb, omb, x2);
    k_dots   <<<dim3(B_N / 64, P_N / 64), 256, 0, stream>>>(xb, ug, dots);
    k_mu     <<<B_N / 4, 256, 0, stream>>>(dots, x2, p2g, y, accs);
    k_final  <<<1, 1, 0, stream>>>(accs, (float*)d_out);
}

// Round 7
// 135.357 us; speedup vs baseline: 1.1333x; 1.0448x over previous
//
#include <hip/hip_runtime.h>
#include <math.h>

typedef unsigned short ushort_t;
typedef __attribute__((ext_vector_type(8))) short short8;
typedef __attribute__((ext_vector_type(4))) float f32x4;

#define B_N 4096
#define D_N 512
#define P_N 256
#define C_N 8

// workspace byte offsets
#define ACC_OFF   0                          // [0]=loss_sum, [1]=omega_sumsq
#define P2G_OFF   256                        // p2 grouped [256] f32
#define X2_OFF    1280                       // x2 [B][C] f32 (atomically accumulated)
#define XB_OFF    132352                     // x bf16 [B][D]
#define OMB_OFF   (XB_OFF + B_N*D_N*2)       // omega bf16 [C][D][D]
#define TPG_OFF   (OMB_OFF + C_N*D_N*D_N*2)  // tp grouped bf16 [C][32][D]
#define UG_OFF    (TPG_OFF + P_N*D_N*2)      // u grouped bf16 [C][32][D]
#define OMBT_OFF  (UG_OFF + P_N*D_N*2)       // omega^T bf16 [C][D][D]
#define MINB_OFF  OMBT_OFF                   // minb [B][C] f32 — aliases ombT (dead after k_u; stream-ordered)

#define MFMA16(a, b, c) __builtin_amdgcn_mfma_f32_16x16x32_bf16(a, b, c, 0, 0, 0)

__device__ inline ushort_t f2bf(float f) {
    union { float f; unsigned u; } v; v.f = f;
    unsigned r = v.u + 0x7FFFu + ((v.u >> 16) & 1u);
    return (ushort_t)(r >> 16);
}

// async global->LDS, 16 B per lane. LDS dst must be wave-uniform; HW writes base + lane*16.
__device__ __forceinline__ void gll16(const ushort_t* g, ushort_t* l) {
    __builtin_amdgcn_global_load_lds((const __attribute__((address_space(1))) void*)g,
                                     (__attribute__((address_space(3))) void*)l, 16, 0, 0);
}

// ---------- cast x -> bf16 ----------
__global__ void k_cast_x(const float* __restrict__ x, ushort_t* __restrict__ xb) {
    int idx = blockIdx.x * 256 + threadIdx.x;
    const float4* x4 = (const float4*)x;
    float4 a = x4[idx * 2], b = x4[idx * 2 + 1];
    union { ushort_t s[8]; uint4 v; } o;
    o.s[0] = f2bf(a.x); o.s[1] = f2bf(a.y); o.s[2] = f2bf(a.z); o.s[3] = f2bf(a.w);
    o.s[4] = f2bf(b.x); o.s[5] = f2bf(b.y); o.s[6] = f2bf(b.z); o.s[7] = f2bf(b.w);
    ((uint4*)xb)[idx] = o.v;
}

// ---------- cast omega -> bf16 (row-major + transposed) + sumsq ----------
__global__ void k_cast_om(const float* __restrict__ omega, ushort_t* __restrict__ omb,
                          ushort_t* __restrict__ ombT, float* __restrict__ oss) {
    int c = blockIdx.z, r0 = blockIdx.y * 64, c0 = blockIdx.x * 64;
    __shared__ ushort_t T[64][72];
    __shared__ float red[4];
    int t = threadIdx.x;
    int r = t >> 2, seg = t & 3;
    const float* src = omega + ((size_t)c * D_N + r0 + r) * D_N + c0 + seg * 16;
    float4 v0 = ((const float4*)src)[0], v1 = ((const float4*)src)[1];
    float4 v2 = ((const float4*)src)[2], v3 = ((const float4*)src)[3];
    float s = v0.x*v0.x + v0.y*v0.y + v0.z*v0.z + v0.w*v0.w
            + v1.x*v1.x + v1.y*v1.y + v1.z*v1.z + v1.w*v1.w
            + v2.x*v2.x + v2.y*v2.y + v2.z*v2.z + v2.w*v2.w
            + v3.x*v3.x + v3.y*v3.y + v3.z*v3.z + v3.w*v3.w;
    union { ushort_t s[16]; uint4 v[2]; } o;
    float vv[16] = {v0.x,v0.y,v0.z,v0.w, v1.x,v1.y,v1.z,v1.w,
                    v2.x,v2.y,v2.z,v2.w, v3.x,v3.y,v3.z,v3.w};
    #pragma unroll
    for (int j = 0; j < 16; ++j) o.s[j] = f2bf(vv[j]);
    uint4* dst = (uint4*)(omb + ((size_t)c * D_N + r0 + r) * D_N + c0 + seg * 16);
    dst[0] = o.v[0]; dst[1] = o.v[1];
    #pragma unroll
    for (int j = 0; j < 16; ++j) T[seg * 16 + j][r] = o.s[j];
    __syncthreads();
    int jr = t >> 2, sg2 = t & 3;
    uint4 w0 = *(uint4*)&T[jr][sg2 * 16];
    uint4 w1 = *(uint4*)&T[jr][sg2 * 16 + 8];
    uint4* dstT = (uint4*)(ombT + ((size_t)c * D_N + c0 + jr) * D_N + r0 + sg2 * 16);
    dstT[0] = w0; dstT[1] = w1;
    #pragma unroll
    for (int off = 32; off > 0; off >>= 1) s += __shfl_down(s, off);
    if ((t & 63) == 0) red[t >> 6] = s;
    __syncthreads();
    if (t == 0) atomicAdd(oss, red[0] + red[1] + red[2] + red[3]);
}

// ---------- tp[c*32+m][i] = sum_k prot[c+8m][k] * om_c[i][k]; p2 fused ----------
__global__ __launch_bounds__(256) void k_tp(const float* __restrict__ prot,
                                            const ushort_t* __restrict__ omb,
                                            ushort_t* __restrict__ tpg,
                                            float* __restrict__ p2g) {
    int i0 = blockIdx.x * 64, c = blockIdx.y;
    __shared__ ushort_t As[32][72];
    __shared__ ushort_t Bs[64][72];
    int t = threadIdx.x, w = t >> 6, lane = t & 63;
    int g = lane >> 4, cl = lane & 15;
    f32x4 acc[2] = {{0,0,0,0},{0,0,0,0}};
    for (int k0 = 0; k0 < D_N; k0 += 64) {
        __syncthreads();
        {
            int m = t >> 3, seg = t & 7;
            const float* ap = prot + ((size_t)(c + 8 * m)) * D_N + k0 + seg * 8;
            float4 u0 = ((const float4*)ap)[0], u1 = ((const float4*)ap)[1];
            union { ushort_t s[8]; uint4 v; } o;
            o.s[0]=f2bf(u0.x); o.s[1]=f2bf(u0.y); o.s[2]=f2bf(u0.z); o.s[3]=f2bf(u0.w);
            o.s[4]=f2bf(u1.x); o.s[5]=f2bf(u1.y); o.s[6]=f2bf(u1.z); o.s[7]=f2bf(u1.w);
            *(uint4*)&As[m][seg * 8] = o.v;
        }
        {
            int r = t >> 2, sg = t & 3;
            const uint4* bp = (const uint4*)(omb + ((size_t)c * D_N + i0 + r) * D_N + k0 + sg * 16);
            *(uint4*)&Bs[r][sg * 16] = bp[0];
            *(uint4*)&Bs[r][sg * 16 + 8] = bp[1];
        }
        __syncthreads();
        #pragma unroll
        for (int kk = 0; kk < 2; ++kk) {
            int koff = kk * 32 + g * 8;
            short8 bfr = *(const short8*)&Bs[w * 16 + cl][koff];
            #pragma unroll
            for (int mt = 0; mt < 2; ++mt) {
                short8 afr = *(const short8*)&As[mt * 16 + cl][koff];
                acc[mt] = MFMA16(afr, bfr, acc[mt]);
            }
        }
    }
    #pragma unroll
    for (int mt = 0; mt < 2; ++mt)
        #pragma unroll
        for (int reg = 0; reg < 4; ++reg) {
            float v = acc[mt][reg];
            int m = mt * 16 + g * 4 + reg;
            int i = i0 + w * 16 + cl;
            tpg[((size_t)c * 32 + m) * D_N + i] = f2bf(v);
            float s = v * v;
            s += __shfl_xor(s, 1); s += __shfl_xor(s, 2);
            s += __shfl_xor(s, 4); s += __shfl_xor(s, 8);
            if (cl == 0) atomicAdd(&p2g[c * 32 + m], s);
        }
}

// ---------- u[c*32+m][j] = sum_i tp[c*32+m][i] * om_c[i][j] (uses ombT) ----------
__global__ __launch_bounds__(256) void k_u(const ushort_t* __restrict__ tpg,
                                           const ushort_t* __restrict__ ombT,
                                           ushort_t* __restrict__ ug) {
    int j0 = blockIdx.x * 64, c = blockIdx.y;
    __shared__ ushort_t As[32][72];
    __shared__ ushort_t Bs[64][72];
    int t = threadIdx.x, w = t >> 6, lane = t & 63;
    int g = lane >> 4, cl = lane & 15;
    f32x4 acc[2] = {{0,0,0,0},{0,0,0,0}};
    for (int k0 = 0; k0 < D_N; k0 += 64) {
        __syncthreads();
        {
            int m = t >> 3, seg = t & 7;
            *(uint4*)&As[m][seg * 8] =
                *(const uint4*)(tpg + ((size_t)c * 32 + m) * D_N + k0 + seg * 8);
        }
        {
            int r = t >> 2, sg = t & 3;
            const uint4* bp = (const uint4*)(ombT + ((size_t)c * D_N + j0 + r) * D_N + k0 + sg * 16);
            *(uint4*)&Bs[r][sg * 16] = bp[0];
            *(uint4*)&Bs[r][sg * 16 + 8] = bp[1];
        }
        __syncthreads();
        #pragma unroll
        for (int kk = 0; kk < 2; ++kk) {
            int koff = kk * 32 + g * 8;
            short8 bfr = *(const short8*)&Bs[w * 16 + cl][koff];
            #pragma unroll
            for (int mt = 0; mt < 2; ++mt) {
                short8 afr = *(const short8*)&As[mt * 16 + cl][koff];
                acc[mt] = MFMA16(afr, bfr, acc[mt]);
            }
        }
    }
    #pragma unroll
    for (int mt = 0; mt < 2; ++mt)
        #pragma unroll
        for (int reg = 0; reg < 4; ++reg) {
            int m = mt * 16 + g * 4 + reg;
            int j = j0 + w * 16 + cl;
            ug[((size_t)c * 32 + m) * D_N + j] = f2bf(acc[mt][reg]);
        }
}

// ---------- fused x2 + dots-min: grid (5, 8, 32) ----------
// blockIdx.x 0..3: x2 i-chunk (128x128 tile, adds ||om_c[i0:i0+128] x_b||^2).
// blockIdx.x == 4: dots slice (128b x 32q for class c) -> minb[b][c] = min_q(p2[q]-2*x.u_q).
// BK=32 double-buffered global_load_lds pipeline: prefetch slab s+1 while computing slab s,
// one barrier per iteration. Swizzle: LDS chunk-pos p of row r holds global chunk (p+r)&3.
__global__ __launch_bounds__(256, 4) void k_x2d(const ushort_t* __restrict__ xb,
                                                const ushort_t* __restrict__ omb,
                                                const ushort_t* __restrict__ ug,
                                                const float* __restrict__ p2g,
                                                float* __restrict__ x2,
                                                float* __restrict__ minb) {
    int c  = blockIdx.y;
    int b0 = blockIdx.z * 128;
    int t = threadIdx.x, w = t >> 6, lane = t & 63;
    int g = lane >> 4, cl = lane & 15;
    int srow = lane >> 2, spos = lane & 3;   // staging: 16 rows x 4 chunk-positions per gll

    __shared__ ushort_t Xs[2][128][32];
    __shared__ ushort_t Os[2][128][32];      // dots path uses rows 0..31 as Us
    __shared__ float red[128][2];

    if (blockIdx.x < 4) {
        int i0 = blockIdx.x * 128;
        int qr = w >> 1, qc = w & 1;
        f32x4 acc[4][4];
        #pragma unroll
        for (int mt = 0; mt < 4; ++mt)
            #pragma unroll
            for (int nt = 0; nt < 4; ++nt) acc[mt][nt] = (f32x4){0,0,0,0};
        // prologue: stage slab 0
        #pragma unroll
        for (int i = 0; i < 2; ++i) {
            int rb = w * 32 + i * 16;
            int r  = rb + srow;
            int cg = (spos + r) & 3;
            gll16(xb + (size_t)(b0 + r) * D_N + cg * 8, &Xs[0][rb][0]);
            gll16(omb + ((size_t)c * D_N + i0 + r) * D_N + cg * 8, &Os[0][rb][0]);
        }
        __syncthreads();
        for (int s = 0; s < 16; ++s) {
            int cb = s & 1, nb = cb ^ 1;
            if (s < 15) {
                int k1 = (s + 1) * 32;
                #pragma unroll
                for (int i = 0; i < 2; ++i) {
                    int rb = w * 32 + i * 16;
                    int r  = rb + srow;
                    int cg = (spos + r) & 3;
                    gll16(xb + (size_t)(b0 + r) * D_N + k1 + cg * 8, &Xs[nb][rb][0]);
                    gll16(omb + ((size_t)c * D_N + i0 + r) * D_N + k1 + cg * 8, &Os[nb][rb][0]);
                }
            }
            short8 a[4], b[4];
            #pragma unroll
            for (int mt = 0; mt < 4; ++mt) {
                int r = qr * 64 + mt * 16 + cl;
                a[mt] = *(const short8*)&Xs[cb][r][((g - r) & 3) * 8];
            }
            #pragma unroll
            for (int nt = 0; nt < 4; ++nt) {
                int r = qc * 64 + nt * 16 + cl;
                b[nt] = *(const short8*)&Os[cb][r][((g - r) & 3) * 8];
            }
            #pragma unroll
            for (int mt = 0; mt < 4; ++mt)
                #pragma unroll
                for (int nt = 0; nt < 4; ++nt)
                    acc[mt][nt] = MFMA16(a[mt], b[nt], acc[mt][nt]);
            __syncthreads();
        }
        // epilogue: row sum-of-squares -> red -> atomic
        #pragma unroll
        for (int mt = 0; mt < 4; ++mt)
            #pragma unroll
            for (int reg = 0; reg < 4; ++reg) {
                float s = 0.f;
                #pragma unroll
                for (int nt = 0; nt < 4; ++nt) s += acc[mt][nt][reg] * acc[mt][nt][reg];
                s += __shfl_xor(s, 1); s += __shfl_xor(s, 2);
                s += __shfl_xor(s, 4); s += __shfl_xor(s, 8);
                if (cl == 0) red[qr * 64 + mt * 16 + g * 4 + reg][qc] = s;
            }
        __syncthreads();
        if (t < 128) atomicAdd(&x2[(size_t)(b0 + t) * C_N + c], red[t][0] + red[t][1]);
    } else {
        // dots slice: 128 b x 32 q (class c). Wave w owns b rows [w*32, w*32+32).
        f32x4 acc[2][2];
        #pragma unroll
        for (int mt = 0; mt < 2; ++mt)
            #pragma unroll
            for (int nt = 0; nt < 2; ++nt) acc[mt][nt] = (f32x4){0,0,0,0};
        #pragma unroll
        for (int i = 0; i < 2; ++i) {
            int rb = w * 32 + i * 16;
            int r  = rb + srow;
            int cg = (spos + r) & 3;
            gll16(xb + (size_t)(b0 + r) * D_N + cg * 8, &Xs[0][rb][0]);
        }
        if (w < 2) {
            int rb = w * 16;
            int r  = rb + srow;
            int cg = (spos + r) & 3;
            gll16(ug + ((size_t)c * 32 + r) * D_N + cg * 8, &Os[0][rb][0]);
        }
        __syncthreads();
        for (int s = 0; s < 16; ++s) {
            int cb = s & 1, nb = cb ^ 1;
            if (s < 15) {
                int k1 = (s + 1) * 32;
                #pragma unroll
                for (int i = 0; i < 2; ++i) {
                    int rb = w * 32 + i * 16;
                    int r  = rb + srow;
                    int cg = (spos + r) & 3;
                    gll16(xb + (size_t)(b0 + r) * D_N + k1 + cg * 8, &Xs[nb][rb][0]);
                }
                if (w < 2) {
                    int rb = w * 16;
                    int r  = rb + srow;
                    int cg = (spos + r) & 3;
                    gll16(ug + ((size_t)c * 32 + r) * D_N + k1 + cg * 8, &Os[nb][rb][0]);
                }
            }
            short8 a[2], b[2];
            #pragma unroll
            for (int mt = 0; mt < 2; ++mt) {
                int r = w * 32 + mt * 16 + cl;
                a[mt] = *(const short8*)&Xs[cb][r][((g - r) & 3) * 8];
            }
            #pragma unroll
            for (int nt = 0; nt < 2; ++nt) {
                int r = nt * 16 + cl;
                b[nt] = *(const short8*)&Os[cb][r][((g - r) & 3) * 8];
            }
            #pragma unroll
            for (int mt = 0; mt < 2; ++mt)
                #pragma unroll
                for (int nt = 0; nt < 2; ++nt)
                    acc[mt][nt] = MFMA16(a[mt], b[nt], acc[mt][nt]);
            __syncthreads();
        }
        // min epilogue: minb[b][c] = min_q (p2[q] - 2*dot)
        #pragma unroll
        for (int mt = 0; mt < 2; ++mt)
            #pragma unroll
            for (int reg = 0; reg < 4; ++reg) {
                float v = INFINITY;
                #pragma unroll
                for (int nt = 0; nt < 2; ++nt) {
                    int q = c * 32 + nt * 16 + cl;
                    v = fminf(v, p2g[q] - 2.f * acc[mt][nt][reg]);
                }
                v = fminf(v, __shfl_xor(v, 1)); v = fminf(v, __shfl_xor(v, 2));
                v = fminf(v, __shfl_xor(v, 4)); v = fminf(v, __shfl_xor(v, 8));
                if (cl == 0)
                    minb[(size_t)(b0 + w * 32 + mt * 16 + g * 4 + reg) * C_N + c] = v;
            }
    }
}

// ---------- per-row mu from x2 + minb -> sigmoid -> sum ----------
__global__ void k_mu(const float* __restrict__ x2, const float* __restrict__ minb,
                     const int* __restrict__ y, float* __restrict__ acc) {
    int t = threadIdx.x;
    int b = blockIdx.x * 256 + t;
    int yb = y[b];
    float d[8];
    #pragma unroll
    for (int cc = 0; cc < 8; ++cc)
        d[cc] = x2[(size_t)b * C_N + cc] + minb[(size_t)b * C_N + cc];
    float pos = d[yb];
    float neg = INFINITY;
    #pragma unroll
    for (int cc = 0; cc < 8; ++cc)
        if (cc != yb) neg = fminf(neg, d[cc]);
    float mu = (pos - neg) / (pos + neg);
    float s = 1.f / (1.f + expf(-mu));
    #pragma unroll
    for (int off = 32; off > 0; off >>= 1) s += __shfl_down(s, off);
    __shared__ float red[4];
    if ((t & 63) == 0) red[t >> 6] = s;
    __syncthreads();
    if (t == 0) atomicAdd(acc, red[0] + red[1] + red[2] + red[3]);
}

__global__ void k_final(const float* __restrict__ accs, float* __restrict__ out) {
    out[0] = accs[0] * (1.f / (float)B_N) + 0.01f * sqrtf(accs[1]);
}

extern "C" void kernel_launch(void* const* d_in, const int* in_sizes, int n_in,
                              void* d_out, int out_size, void* d_ws, size_t ws_size,
                              hipStream_t stream) {
    (void)in_sizes; (void)n_in; (void)out_size; (void)ws_size;
    const float* x     = (const float*)d_in[0];
    const int*   y     = (const int*)d_in[1];
    const float* prot  = (const float*)d_in[2];
    const float* omega = (const float*)d_in[3];

    char* ws = (char*)d_ws;
    float*    accs = (float*)(ws + ACC_OFF);
    float*    p2g  = (float*)(ws + P2G_OFF);
    float*    x2   = (float*)(ws + X2_OFF);
    ushort_t* xb   = (ushort_t*)(ws + XB_OFF);
    ushort_t* omb  = (ushort_t*)(ws + OMB_OFF);
    ushort_t* tpg  = (ushort_t*)(ws + TPG_OFF);
    ushort_t* ug   = (ushort_t*)(ws + UG_OFF);
    ushort_t* ombT = (ushort_t*)(ws + OMBT_OFF);
    float*    minb = (float*)(ws + MINB_OFF);  // aliases ombT — safe: stream-ordered after k_u

    (void)hipMemsetAsync(ws, 0, XB_OFF, stream);  // accs, p2g, x2
    k_cast_x <<<B_N * D_N / 8 / 256, 256, 0, stream>>>(x, xb);
    k_cast_om<<<dim3(8, 8, C_N), 256, 0, stream>>>(omega, omb, ombT, accs + 1);
    k_tp     <<<dim3(8, C_N), 256, 0, stream>>>(prot, omb, tpg, p2g);
    k_u      <<<dim3(8, C_N), 256, 0, stream>>>(tpg, ombT, ug);
    k_x2d    <<<dim3(5, C_N, B_N / 128), 256, 0, stream>>>(xb, omb, ug, p2g, x2, minb);
    k_mu     <<<B_N / 256, 256, 0, stream>>>(x2, minb, y, accs);
    k_final  <<<1, 1, 0, stream>>>(accs, (float*)d_out);
}